// Round 6
// baseline (10054.359 us; speedup 1.0000x reference)
//
#include <hip/hip_runtime.h>

#define B_SZ 32
#define S_LEN 2048
#define I_SZ 256
#define H_SZ 512
#define OUT_MAIN ((size_t)B_SZ * S_LEN * H_SZ)

typedef _Float16 half8 __attribute__((ext_vector_type(8)));
typedef float floatx4 __attribute__((ext_vector_type(4)));
typedef unsigned long long u64;

// ---------------------------------------------------------------------------
// Kernel 1: zero flags; wih16 row-major f16; w2 = W_hh in MFMA-fragment-major
// f16 (frag id = kt*32+mt; w2[((kt*32+mt)*64+lane)*8+e] =
// W[mt*16+(lane&15)][kt*32+(lane>>4)*8+e]); mailbox parity-0 = f16 h0.
// Mailbox u64 layout: [parity(2)][gb(8)][slice(4)][bb(4)][j4(32)].
// ---------------------------------------------------------------------------
__global__ void rnn_init(const float* __restrict__ wih, const float* __restrict__ whh,
                         const float* __restrict__ h0,
                         _Float16* __restrict__ wih16, _Float16* __restrict__ w2,
                         u64* __restrict__ mbox, unsigned* __restrict__ flags) {
  int idx = blockIdx.x * blockDim.x + threadIdx.x;
  int stride = gridDim.x * blockDim.x;
  if (idx < 2048) flags[idx] = 0;  // ws poisoned every call; must re-zero
  for (int i = idx; i < H_SZ * I_SZ; i += stride) wih16[i] = (_Float16)wih[i];
  for (int o = idx; o < H_SZ * H_SZ; o += stride) {
    const int e = o & 7;
    const int lane = (o >> 3) & 63;
    const int mt = (o >> 9) & 31;
    const int kt = o >> 14;
    const int m = mt * 16 + (lane & 15);
    const int k = kt * 32 + (lane >> 4) * 8 + e;
    w2[o] = (_Float16)whh[(size_t)m * H_SZ + k];
  }
  // h0 -> mailbox parity 0
  for (int i = idx; i < 8 * 4 * 4 * 32; i += stride) {
    const int j4 = i & 31;
    const int bb = (i >> 5) & 3;
    const int s  = (i >> 7) & 3;
    const int gb = i >> 9;
    const int b = gb * 4 + bb;
    const int j = s * 128 + j4 * 4;
    union { _Float16 h[4]; u64 q; } pk;
    pk.h[0] = (_Float16)h0[(size_t)b * H_SZ + j];
    pk.h[1] = (_Float16)h0[(size_t)b * H_SZ + j + 1];
    pk.h[2] = (_Float16)h0[(size_t)b * H_SZ + j + 2];
    pk.h[3] = (_Float16)h0[(size_t)b * H_SZ + j + 3];
    mbox[i] = pk.q;
  }
}

// ---------------------------------------------------------------------------
// Kernel 2: z' = inputs @ W_ih^T + b_ih + b_hh -> d_out in [B,S,H] layout.
// (unchanged)
// ---------------------------------------------------------------------------
__launch_bounds__(256, 2)
__global__ void rnn_zin(const float* __restrict__ inputs, const _Float16* __restrict__ wih16,
                        const float* __restrict__ bih, const float* __restrict__ bhh,
                        float* __restrict__ out) {
  const int wave = threadIdx.x >> 6;
  const int lane = threadIdx.x & 63;
  const int col = lane & 15;
  const int quad = lane >> 4;
  const int m0 = blockIdx.x * 64 + wave * 16;

  floatx4 acc[32];
#pragma unroll
  for (int nt = 0; nt < 32; ++nt) acc[nt] = (floatx4){0.f, 0.f, 0.f, 0.f};

#pragma unroll
  for (int kt = 0; kt < 8; ++kt) {
    const float* ap = inputs + (size_t)(m0 + col) * I_SZ + kt * 32 + quad * 8;
    float4 a0 = *(const float4*)(ap);
    float4 a1 = *(const float4*)(ap + 4);
    half8 af;
    af[0] = (_Float16)a0.x; af[1] = (_Float16)a0.y; af[2] = (_Float16)a0.z; af[3] = (_Float16)a0.w;
    af[4] = (_Float16)a1.x; af[5] = (_Float16)a1.y; af[6] = (_Float16)a1.z; af[7] = (_Float16)a1.w;
#pragma unroll
    for (int nt = 0; nt < 32; ++nt) {
      half8 bf = *(const half8*)(wih16 + (size_t)(nt * 16 + col) * I_SZ + kt * 32 + quad * 8);
      acc[nt] = __builtin_amdgcn_mfma_f32_16x16x32_f16(af, bf, acc[nt], 0, 0, 0);
    }
  }

#pragma unroll
  for (int nt = 0; nt < 32; ++nt) {
    const int j = nt * 16 + col;
    const float bias = bih[j] + bhh[j];
#pragma unroll
    for (int r = 0; r < 4; ++r) {
      const int m = m0 + quad * 4 + r;
      out[(size_t)m * H_SZ + j] = acc[nt][r] + bias;
    }
  }
}

// ---------------------------------------------------------------------------
// Kernel 3: wide persistent recurrence, 32 blocks = 8 groups (gb = bid&7;
// blocks gb, gb+8, gb+16, gb+24 share an XCD under round-robin dispatch so
// the exchange is served by that XCD's L2) x 4 j-slices (bid>>3).
// Group gb owns batches [gb*4,+4); block owns j in [slice*128,+128).
// W slice pinned: 2 m-tiles/wave x 16 kt = 128 regs/thread. NO LDS.
// Exchange: 1 KB/block f16 h via relaxed agent-scope u64 atomics; B-frags
// loaded DIRECTLY from the mailbox. Poll is ONE thread per block (s_sleep
// backoff) + s_barrier release — 32 spinners chip-wide, so spin traffic
// cannot starve the h-store acks / flag stores at the coherence point
// (the suspected r5 livelock). Out stores after the flag, off the path.
// ---------------------------------------------------------------------------
__launch_bounds__(256, 1)
__global__ void rnn_steps(const _Float16* __restrict__ w2, float* __restrict__ out,
                          u64* __restrict__ mbox, unsigned* __restrict__ flags) {
  const int tid = threadIdx.x;
  const int w = tid >> 6;         // wave 0..3
  const int lane = tid & 63;
  const int col = lane & 15;
  const int quad = lane >> 4;
  const int gb = blockIdx.x & 7;  // group (XCD id under round-robin dispatch)
  const int slice = blockIdx.x >> 3;
  const int bb = col & 3;         // mailbox batch (cols 4..15 duplicate 0..3)
  const int b = gb * 4 + bb;      // global batch for this lane's MFMA column
  const int jw = slice * 128 + w * 32;  // wave's output-row base

  unsigned* fs = flags + (size_t)(gb * 4 + slice) * 16;
  unsigned* f0 = flags + (size_t)(gb * 4 + ((slice + 1) & 3)) * 16;
  unsigned* f1 = flags + (size_t)(gb * 4 + ((slice + 2) & 3)) * 16;
  unsigned* f2 = flags + (size_t)(gb * 4 + ((slice + 3) & 3)) * 16;

  // ---- pin W: wave w owns global m-tiles slice*8 + w*2 + {0,1} ----
  half8 wReg[2][16];
#pragma unroll
  for (int mm = 0; mm < 2; ++mm) {
    const int mtg = slice * 8 + w * 2 + mm;
#pragma unroll
    for (int kt = 0; kt < 16; ++kt)
      wReg[mm][kt] = *(const half8*)(w2 + ((size_t)(kt * 32 + mtg) * 64 + lane) * 8);
  }

#pragma unroll 1
  for (int t = 0; t < S_LEN; ++t) {
    if (t > 0) {
      __builtin_amdgcn_sched_barrier(0);
      if (tid == 0) {  // single spinner per block: no coherence-point storm
        const unsigned tgt = (unsigned)t;
        for (;;) {
          const unsigned a = __hip_atomic_load(f0, __ATOMIC_RELAXED, __HIP_MEMORY_SCOPE_AGENT);
          const unsigned c = __hip_atomic_load(f1, __ATOMIC_RELAXED, __HIP_MEMORY_SCOPE_AGENT);
          const unsigned d = __hip_atomic_load(f2, __ATOMIC_RELAXED, __HIP_MEMORY_SCOPE_AGENT);
          if (((a >= tgt) & (c >= tgt) & (d >= tgt)) != 0) break;
          __builtin_amdgcn_s_sleep(1);  // backoff: keep the MALL/L2 queue clear
        }
      }
      __builtin_amdgcn_s_barrier();  // release block; no LDS/vm drain needed
      __builtin_amdgcn_sched_barrier(0);
      asm volatile("" ::: "memory");  // don't hoist mailbox loads above release
    }

    // ---- B-frags straight from mailbox parity t&1 (burst of 32 u64 loads) ----
    const u64* mb = mbox + (size_t)(t & 1) * 4096 + (size_t)gb * 512;
    half8 hf[16];
#pragma unroll
    for (int kt = 0; kt < 16; ++kt) {
      const size_t o = (size_t)(kt >> 2) * 128 + (size_t)bb * 32 + (kt & 3) * 8 + quad * 2;
      u64 lo = __hip_atomic_load(mb + o,     __ATOMIC_RELAXED, __HIP_MEMORY_SCOPE_AGENT);
      u64 hi = __hip_atomic_load(mb + o + 1, __ATOMIC_RELAXED, __HIP_MEMORY_SCOPE_AGENT);
      union { u64 q[2]; half8 h; } cv;
      cv.q[0] = lo; cv.q[1] = hi;
      hf[kt] = cv.h;
    }

    // ---- z_t for own rows (normal loads; in-place z region of out) ----
    float4 zf[2];
#pragma unroll
    for (int mm = 0; mm < 2; ++mm)
      zf[mm] = *(const float4*)(out + ((size_t)b * S_LEN + t) * H_SZ + jw + mm * 16 + quad * 4);

    // ---- 32 MFMA: acc[j-rows, batch-cols] += W_slice . h ----
    floatx4 acc0 = (floatx4){0.f, 0.f, 0.f, 0.f};
    floatx4 acc1 = (floatx4){0.f, 0.f, 0.f, 0.f};
#pragma unroll
    for (int kt = 0; kt < 16; ++kt) {
      acc0 = __builtin_amdgcn_mfma_f32_16x16x32_f16(wReg[0][kt], hf[kt], acc0, 0, 0, 0);
      acc1 = __builtin_amdgcn_mfma_f32_16x16x32_f16(wReg[1][kt], hf[kt], acc1, 0, 0, 0);
    }

    // ---- epilogue: h = relu(z + acc); publish h (cols 0..3 only) ----
    float4 hv[2];
#pragma unroll
    for (int mm = 0; mm < 2; ++mm) {
      const floatx4 a = (mm == 0) ? acc0 : acc1;
      hv[mm].x = fmaxf(zf[mm].x + a[0], 0.f);
      hv[mm].y = fmaxf(zf[mm].y + a[1], 0.f);
      hv[mm].z = fmaxf(zf[mm].z + a[2], 0.f);
      hv[mm].w = fmaxf(zf[mm].w + a[3], 0.f);
    }
    u64* mo = mbox + (size_t)((t + 1) & 1) * 4096 + (size_t)gb * 512 + (size_t)slice * 128;
    if (col < 4) {
#pragma unroll
      for (int mm = 0; mm < 2; ++mm) {
        union { _Float16 h[4]; u64 q; } pk;
        pk.h[0] = (_Float16)hv[mm].x; pk.h[1] = (_Float16)hv[mm].y;
        pk.h[2] = (_Float16)hv[mm].z; pk.h[3] = (_Float16)hv[mm].w;
        // u64 index: bb*32 + (w*32 + mm*16 + quad*4)/4
        __hip_atomic_store(mo + (size_t)bb * 32 + w * 8 + mm * 4 + quad, pk.q,
                           __ATOMIC_RELAXED, __HIP_MEMORY_SCOPE_AGENT);
      }
    }

    // Drain h-stores (tiny, L2 ack), sync waves, publish flag.
    asm volatile("s_waitcnt vmcnt(0)" ::: "memory");
    __syncthreads();
    if (tid == 0)
      __hip_atomic_store(fs, (unsigned)(t + 1), __ATOMIC_RELAXED, __HIP_MEMORY_SCOPE_AGENT);

    // ---- out stores after the flag — off the exchange critical path ----
    if (col < 4) {
#pragma unroll
      for (int mm = 0; mm < 2; ++mm) {
        const size_t zi = ((size_t)b * S_LEN + t) * H_SZ + jw + mm * 16 + quad * 4;
        *(float4*)(out + zi) = hv[mm];  // in-place z -> h
        if (t == S_LEN - 1)
          *(float4*)(out + OUT_MAIN + (size_t)b * H_SZ + jw + mm * 16 + quad * 4) = hv[mm];
      }
    }
  }
}

extern "C" void kernel_launch(void* const* d_in, const int* in_sizes, int n_in,
                              void* d_out, int out_size, void* d_ws, size_t ws_size,
                              hipStream_t stream) {
  (void)in_sizes; (void)n_in; (void)out_size; (void)ws_size;
  const float* inputs = (const float*)d_in[0];
  const float* h0     = (const float*)d_in[1];
  const float* wih    = (const float*)d_in[2];
  const float* whh    = (const float*)d_in[3];
  const float* bih    = (const float*)d_in[4];
  const float* bhh    = (const float*)d_in[5];
  float* out = (float*)d_out;

  char* ws = (char*)d_ws;
  unsigned* flags  = (unsigned*)(ws);                          // 8 KB (2048 u32)
  _Float16* wih16 = (_Float16*)(ws + 8192);                    // 256 KB
  _Float16* w2    = (_Float16*)(ws + 8192 + 262144);           // 512 KB (frag-major W_hh)
  u64*      mbox  = (u64*)(ws + 8192 + 262144 + 524288);       // 64 KB h mailbox

  rnn_init<<<64, 256, 0, stream>>>(wih, whh, h0, wih16, w2, mbox, flags);
  rnn_zin<<<1024, 256, 0, stream>>>(inputs, wih16, bih, bhh, out);
  rnn_steps<<<32, 256, 0, stream>>>(w2, out, mbox, flags);
}

// Round 7
// 7788.140 us; speedup vs baseline: 1.2910x; 1.2910x over previous
//
#include <hip/hip_runtime.h>

#define B_SZ 32
#define S_LEN 2048
#define I_SZ 256
#define H_SZ 512
#define OUT_MAIN ((size_t)B_SZ * S_LEN * H_SZ)

#define KT_TOT 16   // 512 k in 16 tiles of 32
#define KT_REG 12   // k-tiles pinned in regs (8 mt x 12 kt x 4 = 384 slots/thread)
#define KT_LDS 4    // k-tiles resident in LDS (128 KB, frag-major)

typedef _Float16 half8 __attribute__((ext_vector_type(8)));
typedef float floatx4 __attribute__((ext_vector_type(4)));
typedef unsigned long long u64;

// LDS-only barrier: global loads/stores stay in flight across it.
// sched_barrier(0) fences stop hipcc migrating ds ops across (rule #18).
#define LDS_BARRIER()                                         \
  do {                                                        \
    __builtin_amdgcn_sched_barrier(0);                        \
    asm volatile("s_waitcnt lgkmcnt(0)" ::: "memory");        \
    __builtin_amdgcn_s_barrier();                             \
    __builtin_amdgcn_sched_barrier(0);                        \
  } while (0)

// ---------------------------------------------------------------------------
// Kernel 1: wih16 row-major f16; w2 = W_hh MFMA-fragment-major f16
// (w2[((kt*32+mt)*64+lane)*8+e] = W[mt*16+(lane&15)][kt*32+(lane>>4)*8+e]);
// h16f = h0 in B-FRAGMENT-major f16: h16f[((g*16+kt)*64+l)*8+e] =
//   h0[g*16+(l&15)][kt*32+((l>>4)&3)*8+e]  (g = block group).
// ---------------------------------------------------------------------------
__global__ void rnn_init(const float* __restrict__ wih, const float* __restrict__ whh,
                         const float* __restrict__ h0,
                         _Float16* __restrict__ wih16, _Float16* __restrict__ w2,
                         _Float16* __restrict__ h16f) {
  int idx = blockIdx.x * blockDim.x + threadIdx.x;
  int stride = gridDim.x * blockDim.x;
  for (int i = idx; i < H_SZ * I_SZ; i += stride) wih16[i] = (_Float16)wih[i];
  for (int o = idx; o < H_SZ * H_SZ; o += stride) {
    const int e = o & 7;
    const int lane = (o >> 3) & 63;
    const int mt = (o >> 9) & 31;
    const int kt = o >> 14;
    const int m = mt * 16 + (lane & 15);
    const int k = kt * 32 + (lane >> 4) * 8 + e;
    w2[o] = (_Float16)whh[(size_t)m * H_SZ + k];
  }
  for (int i = idx; i < 2 * 16 * 64 * 8; i += stride) {
    const int e = i & 7;
    const int l = (i >> 3) & 63;
    const int kt = (i >> 9) & 15;
    const int g = i >> 13;
    const int b = g * 16 + (l & 15);
    const int k = kt * 32 + ((l >> 4) & 3) * 8 + e;
    h16f[i] = (_Float16)h0[(size_t)b * H_SZ + k];
  }
}

// ---------------------------------------------------------------------------
// Kernel 2: z' = inputs @ W_ih^T + b_ih + b_hh -> d_out in [B,S,H] layout.
// (unchanged)
// ---------------------------------------------------------------------------
__launch_bounds__(256, 2)
__global__ void rnn_zin(const float* __restrict__ inputs, const _Float16* __restrict__ wih16,
                        const float* __restrict__ bih, const float* __restrict__ bhh,
                        float* __restrict__ out) {
  const int wave = threadIdx.x >> 6;
  const int lane = threadIdx.x & 63;
  const int col = lane & 15;
  const int quad = lane >> 4;
  const int m0 = blockIdx.x * 64 + wave * 16;

  floatx4 acc[32];
#pragma unroll
  for (int nt = 0; nt < 32; ++nt) acc[nt] = (floatx4){0.f, 0.f, 0.f, 0.f};

#pragma unroll
  for (int kt = 0; kt < 8; ++kt) {
    const float* ap = inputs + (size_t)(m0 + col) * I_SZ + kt * 32 + quad * 8;
    float4 a0 = *(const float4*)(ap);
    float4 a1 = *(const float4*)(ap + 4);
    half8 af;
    af[0] = (_Float16)a0.x; af[1] = (_Float16)a0.y; af[2] = (_Float16)a0.z; af[3] = (_Float16)a0.w;
    af[4] = (_Float16)a1.x; af[5] = (_Float16)a1.y; af[6] = (_Float16)a1.z; af[7] = (_Float16)a1.w;
#pragma unroll
    for (int nt = 0; nt < 32; ++nt) {
      half8 bf = *(const half8*)(wih16 + (size_t)(nt * 16 + col) * I_SZ + kt * 32 + quad * 8);
      acc[nt] = __builtin_amdgcn_mfma_f32_16x16x32_f16(af, bf, acc[nt], 0, 0, 0);
    }
  }

#pragma unroll
  for (int nt = 0; nt < 32; ++nt) {
    const int j = nt * 16 + col;
    const float bias = bih[j] + bhh[j];
#pragma unroll
    for (int r = 0; r < 4; ++r) {
      const int m = m0 + quad * 4 + r;
      out[(size_t)m * H_SZ + j] = acc[nt][r] + bias;
    }
  }
}

// ---------------------------------------------------------------------------
// Kernel 3: CU-local recurrence, 2 blocks x 256 threads (4 waves, 1/SIMD,
// 512-reg budget). Block gb owns batches [gb*16,+16); wave w owns j in
// [w*128,+128) (8 m-tiles). W_hh: kt 0..11 pinned (384 slots), kt 12..15 in
// LDS frag-major (128 KB). h in LDS in B-FRAGMENT-major layout: every hf
// read is lane-contiguous (kt*1024 + lane*16) => ZERO bank conflicts; the
// h write is 4 contiguous ds_write_b64 => ZERO conflicts.
// Reads are group-pipelined at source level (hf ping-pong groups of 4 one
// stage ahead; all 8 wl reads of a tail kt issued before its MFMAs) so the
// compiler can hide LDS latency — r3/r4's serialized-read bottleneck.
// ---------------------------------------------------------------------------
__launch_bounds__(256, 1)
__global__ void rnn_steps(const _Float16* __restrict__ w2, float* __restrict__ out,
                          const _Float16* __restrict__ h16f) {
  __shared__ _Float16 lds_w[KT_LDS * 32 * 64 * 8];  // 131072 B, frag-major
  __shared__ _Float16 lds_h[16 * 64 * 8];           // 16384 B, frag-major

  const int tid = threadIdx.x;
  const int w = tid >> 6;        // wave 0..3
  const int lane = tid & 63;
  const int col = lane & 15;
  const int quad = lane >> 4;
  const int gb = blockIdx.x;     // 0..1
  const int b = gb * 16 + col;   // this lane's batch (MFMA B column)
  const int w8 = w * 8;

  const char* lds_hc = (const char*)lds_h;
  const char* lds_wc = (const char*)lds_w;
  const int lane16 = lane * 16;

  // ---- stage W k-tiles 12..15 into LDS (linear copy of frag-major tail) ----
  {
    const uint4* src = (const uint4*)(w2 + (size_t)KT_REG * 32 * 64 * 8);
    uint4* dst = (uint4*)lds_w;
    for (int i = tid; i < (KT_LDS * 32 * 64 * 8) / 8; i += 256) dst[i] = src[i];
  }
  // ---- stage h0 into LDS (already frag-major in h16f; linear copy) ----
  {
    const u64* src = (const u64*)(h16f + (size_t)gb * 8192);
    u64* dst = (u64*)lds_h;
    for (int i = tid; i < 2048; i += 256) dst[i] = src[i];
  }

  // ---- pin W k-tiles 0..11: wave w owns m-tiles w*8 .. w*8+7 ----
  half8 wReg[8][KT_REG];
#pragma unroll
  for (int mm = 0; mm < 8; ++mm)
#pragma unroll
    for (int kt = 0; kt < KT_REG; ++kt)
      wReg[mm][kt] = *(const half8*)(w2 + ((size_t)(kt * 32 + w8 + mm) * 64 + lane) * 8);

  __syncthreads();  // one-time full barrier: staging complete

  // per-lane address pieces
  const float* zbase = out + (size_t)b * S_LEN * H_SZ + w * 128 + quad * 4;
  // h write: byte = w*4096 + (quad>>1)*256 + col*16 + (quad&1)*8  (+ per-mm)
  char* hw = (char*)lds_h + w * 4096 + (quad >> 1) * 256 + col * 16 + (quad & 1) * 8;

#define HRD(kt) (*(const half8*)(lds_hc + (kt)*1024 + lane16))
#define WRD(kt, mm) (*(const half8*)(lds_wc + ((size_t)(((kt)-12) * 32 + w8 + (mm))) * 1024 + lane16))

#pragma unroll 1
  for (int t = 0; t < S_LEN; ++t) {
    floatx4 acc[8];
#pragma unroll
    for (int mm = 0; mm < 8; ++mm) acc[mm] = (floatx4){0.f, 0.f, 0.f, 0.f};

    half8 hA[4], hB[4];
#pragma unroll
    for (int q = 0; q < 4; ++q) hA[q] = HRD(q);  // group 0 in flight

    // z_t loads (global, vmcnt — hidden under the whole MFMA phase)
    float4 zf[8];
#pragma unroll
    for (int mm = 0; mm < 8; ++mm) zf[mm] = *(const float4*)(zbase + (size_t)t * H_SZ + mm * 16);

#pragma unroll
    for (int q = 0; q < 4; ++q) hB[q] = HRD(4 + q);  // group 1 in flight
#pragma unroll
    for (int q = 0; q < 4; ++q)
#pragma unroll
      for (int mm = 0; mm < 8; ++mm)
        acc[mm] = __builtin_amdgcn_mfma_f32_16x16x32_f16(wReg[mm][q], hA[q], acc[mm], 0, 0, 0);

#pragma unroll
    for (int q = 0; q < 4; ++q) hA[q] = HRD(8 + q);  // group 2
#pragma unroll
    for (int q = 0; q < 4; ++q)
#pragma unroll
      for (int mm = 0; mm < 8; ++mm)
        acc[mm] = __builtin_amdgcn_mfma_f32_16x16x32_f16(wReg[mm][4 + q], hB[q], acc[mm], 0, 0, 0);

#pragma unroll
    for (int q = 0; q < 4; ++q) hB[q] = HRD(12 + q);  // group 3 (tail h)
#pragma unroll
    for (int q = 0; q < 4; ++q)
#pragma unroll
      for (int mm = 0; mm < 8; ++mm)
        acc[mm] = __builtin_amdgcn_mfma_f32_16x16x32_f16(wReg[mm][8 + q], hA[q], acc[mm], 0, 0, 0);

    // ---- tail: W k-tiles 12..15 from LDS; all 8 wl reads issued per kt ----
#pragma unroll
    for (int kt = 12; kt < 16; ++kt) {
      half8 wl[8];
#pragma unroll
      for (int mm = 0; mm < 8; ++mm) wl[mm] = WRD(kt, mm);
#pragma unroll
      for (int mm = 0; mm < 8; ++mm)
        acc[mm] = __builtin_amdgcn_mfma_f32_16x16x32_f16(wl[mm], hB[kt - 12], acc[mm], 0, 0, 0);
    }

    // ---- epilogue: h = relu(z + acc) ----
    float4 hv[8];
#pragma unroll
    for (int mm = 0; mm < 8; ++mm) {
      hv[mm].x = fmaxf(zf[mm].x + acc[mm][0], 0.f);
      hv[mm].y = fmaxf(zf[mm].y + acc[mm][1], 0.f);
      hv[mm].z = fmaxf(zf[mm].z + acc[mm][2], 0.f);
      hv[mm].w = fmaxf(zf[mm].w + acc[mm][3], 0.f);
    }

    LDS_BARRIER();  // all reads of h_{t-1} complete; safe to overwrite lds_h

    // frag-major h write: per mm one u64, 64 lanes contiguous (conflict-free)
#pragma unroll
    for (int mm = 0; mm < 8; ++mm) {
      union { _Float16 h[4]; u64 q; } pk;
      pk.h[0] = (_Float16)hv[mm].x; pk.h[1] = (_Float16)hv[mm].y;
      pk.h[2] = (_Float16)hv[mm].z; pk.h[3] = (_Float16)hv[mm].w;
      *(u64*)(hw + ((mm >> 1) * 1024 + (mm & 1) * 512)) = pk.q;
    }

    LDS_BARRIER();  // h_t visible to all waves

    // out stores: fire-and-forget (vmcnt rides across lgkm-only barriers)
#pragma unroll
    for (int mm = 0; mm < 8; ++mm) {
      *(float4*)(const_cast<float*>(zbase) + (size_t)t * H_SZ + mm * 16) = hv[mm];
      if (t == S_LEN - 1)
        *(float4*)(out + OUT_MAIN + (size_t)b * H_SZ + w * 128 + mm * 16 + quad * 4) = hv[mm];
    }
  }
#undef HRD
#undef WRD
}

extern "C" void kernel_launch(void* const* d_in, const int* in_sizes, int n_in,
                              void* d_out, int out_size, void* d_ws, size_t ws_size,
                              hipStream_t stream) {
  (void)in_sizes; (void)n_in; (void)out_size; (void)ws_size;
  const float* inputs = (const float*)d_in[0];
  const float* h0     = (const float*)d_in[1];
  const float* wih    = (const float*)d_in[2];
  const float* whh    = (const float*)d_in[3];
  const float* bih    = (const float*)d_in[4];
  const float* bhh    = (const float*)d_in[5];
  float* out = (float*)d_out;

  char* ws = (char*)d_ws;
  _Float16* wih16 = (_Float16*)(ws);                       // 256 KB
  _Float16* w2    = (_Float16*)(ws + 262144);              // 512 KB (frag-major W_hh)
  _Float16* h16f  = (_Float16*)(ws + 262144 + 524288);     // 32 KB (frag-major h0)

  rnn_init<<<64, 256, 0, stream>>>(wih, whh, h0, wih16, w2, h16f);
  rnn_zin<<<1024, 256, 0, stream>>>(inputs, wih16, bih, bhh, out);
  rnn_steps<<<2, 256, 0, stream>>>(w2, out, h16f);
}